// Round 6
// baseline (115.287 us; speedup 1.0000x reference)
//
#include <hip/hip_runtime.h>
#include <hip/hip_bf16.h>

// Block-circulant conv == GEMM  out[b,oc,r] = sum_k A[b*1024+r, k] * B[k, oc]
//   A = im2col(x) per batch, contiguous (1024, 2304) view (reference reshape).
//   B[k,oc] = w[oc>>6][k>>6][((oc&63)-(k&63))&63]  (circulant expansion)
//
// R6: GEMM restructured for latency hiding — R5 ran 1 block/CU (512 thr,
//     grid 256): every barrier drained ALL resident waves together.
//     Now block-tile 64x128, 4 waves (256 thr), wave-tile 32x64, full-K
//     (no k-interleave/LDS-combine), grid 512 = 2 independent blocks/CU;
//     one block's MFMA covers the other's barrier/vmcnt drain (m114).
//     LDS 48 KB/block dbuf. XOR swizzle + raw vmcnt(6) pipeline kept.
//     Prep byte-identical to R5 (known good).

#define QK 2304
#define MROWS 8192
#define NOC 512
#define QB 36

typedef __attribute__((ext_vector_type(8))) short short8;
typedef __attribute__((ext_vector_type(4))) float floatx4;

__device__ __forceinline__ ushort f2bf(float f) {
    __hip_bfloat16 h = __float2bfloat16(f);
    return *reinterpret_cast<ushort*>(&h);
}

__device__ __forceinline__ void async16(const void* g, void* l) {
    __builtin_amdgcn_global_load_lds((const __attribute__((address_space(1))) void*)g,
                                     (__attribute__((address_space(3))) void*)l, 16, 0, 0);
}

// ---------------- prep: A im2col (shifted copy) + B circulant expand ----------------
#define PREP_A_BLOCKS 18432   // 8 b * 2304 feat
#define PREP_B_BLOCKS 576     // 512 rows * 288 8-elem chunks / 256

__global__ __launch_bounds__(256) void bcc_prep(const float* __restrict__ x,
                                                const float* __restrict__ w,
                                                ushort* __restrict__ wsA,
                                                ushort* __restrict__ wsB) {
    if (blockIdx.x < PREP_A_BLOCKS) {
        const int bb   = blockIdx.x / 2304;           // batch (scalar)
        const int feat = blockIdx.x - bb * 2304;      // 0..2303 (scalar)
        const int c  = feat / 9, kk = feat - c * 9;
        const int di = kk / 3, dj = kk - di * 3;
        const int off = (di - 1) * 32 + (dj - 1);
        const int loc0 = threadIdx.x * 4;             // 4 elems/thread
        const float* xb = x + (size_t)bb * 262144;

        const bool row_ok = (unsigned)((loc0 >> 5) + di - 1) < 32u;
        const int base = c * 1024 + loc0 + off;
        ushort u[4];
        #pragma unroll
        for (int e = 0; e < 4; ++e) {
            int idx = base + e;
            int safe = idx < 0 ? 0 : (idx > 262143 ? 262143 : idx);
            float v = xb[safe];
            int wi = ((loc0 + e) & 31) + dj - 1;
            bool ok = row_ok && ((unsigned)wi < 32u);
            u[e] = f2bf(ok ? v : 0.f);
        }
        *(ushort4*)&wsA[((size_t)bb * 2304 + feat) * 1024 + loc0] =
            make_ushort4(u[0], u[1], u[2], u[3]);
    } else {
        int t = (blockIdx.x - PREP_A_BLOCKS) * 256 + threadIdx.x;  // 0..147455
        int n = t / 288;
        int o = t - n * 288;
        int p = n >> 6, tt = n & 63;
        int k0 = o * 8;
        ushort u[8];
        #pragma unroll
        for (int e = 0; e < 8; ++e) {
            int k = k0 + e;
            int q = k >> 6, s = k & 63;
            u[e] = f2bf(w[(p * QB + q) * 64 + ((tt - s) & 63)]);
        }
        *(ushort4*)&wsB[(size_t)n * QK + k0]     = make_ushort4(u[0], u[1], u[2], u[3]);
        *(ushort4*)&wsB[(size_t)n * QK + k0 + 4] = make_ushort4(u[4], u[5], u[6], u[7]);
    }
}

// ---------------- main GEMM: 64x128 tile, 4 waves, wave-tile 32x64,
// ---------------- full-K, dbuf + raw vmcnt(6), grid 512 (2 blocks/CU) ------
__global__ __launch_bounds__(256) void bcc_mfma(const ushort* __restrict__ A,
                                                const ushort* __restrict__ Bm,
                                                float* __restrict__ out) {
    __shared__ ushort Asm[2][64 * 64];    //  8 KB per buf
    __shared__ ushort Bsm[2][128 * 64];   // 16 KB per buf   (total 48 KB)

    const int tid = threadIdx.x;
    const int l = tid & 63, w = tid >> 6;      // 4 waves
    const int wm = w & 1, wn = w >> 1;         // 2x2 wave grid, tile 32m x 64n

    // XCD-affinity: 4 blocks sharing an A m-tile -> same (lin&7) == XCD
    const int lin = blockIdx.x;                // 0..511
    const int n_idx = (lin >> 3) & 3;          // 0..3
    const int m_idx = ((lin >> 5) << 3) | (lin & 7);   // 0..127
    const int n0 = n_idx * 128;
    const int m0 = m_idx * 64;
    const int b  = m0 >> 10, r0 = m0 & 1023;

    const int lr = l & 15, lq = l >> 4;        // quarter-wave split
    const int lrow = l >> 3;                   // staging row in 8-group
    const int lkoff = ((l & 7) ^ (lrow & 7)) * 8;  // swizzled source chunk

    floatx4 acc[2][4];
    #pragma unroll
    for (int i = 0; i < 2; ++i)
        #pragma unroll
        for (int j = 0; j < 4; ++j) acc[i][j] = (floatx4){0.f, 0.f, 0.f, 0.f};

    // --- staging: per wave per buffer: 2 x A (8 rows) + 4 x B (8 rows) ---
    auto stage = [&](int q, int buf) {
        const int kb = q * 64;
        #pragma unroll
        for (int t = 0; t < 2; ++t) {
            int row8 = w * 16 + t * 8;         // A rows 0..63
            async16(A + ((size_t)(m0 + row8 + lrow) * QK + kb + lkoff),
                    &Asm[buf][row8 * 64]);
        }
        #pragma unroll
        for (int t = 0; t < 4; ++t) {
            int row8 = w * 32 + t * 8;         // B rows 0..127
            async16(Bm + ((size_t)(n0 + row8 + lrow) * QK + kb + lkoff),
                    &Bsm[buf][row8 * 64]);
        }
    };

    stage(0, 0);
    int buf = 0;
    for (int q = 0; q < QB; ++q) {
        if (q + 1 < QB) {
            stage(q + 1, buf ^ 1);
            asm volatile("s_waitcnt vmcnt(6)" ::: "memory");
        } else {
            asm volatile("s_waitcnt vmcnt(0)" ::: "memory");
        }
        __builtin_amdgcn_s_barrier();
        asm volatile("" ::: "memory");

        #pragma unroll
        for (int ks = 0; ks < 2; ++ks) {
            const int ca = ks * 4 + lq;        // logical 16B chunk
            short8 av[2], bv[4];
            #pragma unroll
            for (int i = 0; i < 2; ++i) {
                int Ra = wm * 32 + i * 16 + lr;
                av[i] = *(const short8*)&Asm[buf][Ra * 64 + ((ca ^ (Ra & 7)) * 8)];
            }
            #pragma unroll
            for (int j = 0; j < 4; ++j) {
                int Rb = wn * 64 + j * 16 + lr;
                bv[j] = *(const short8*)&Bsm[buf][Rb * 64 + ((ca ^ (Rb & 7)) * 8)];
            }
            // operand-swapped: D rows = oc, cols = r (r-contiguous stores)
            #pragma unroll
            for (int i = 0; i < 2; ++i)
                #pragma unroll
                for (int j = 0; j < 4; ++j)
                    acc[i][j] = __builtin_amdgcn_mfma_f32_16x16x32_bf16(bv[j], av[i], acc[i][j], 0, 0, 0);
        }

        asm volatile("" ::: "memory");
        __builtin_amdgcn_s_barrier();
        buf ^= 1;
    }

    // epilogue: out[b][oc][r]; 16-lane groups cover 64B-contiguous r
    #pragma unroll
    for (int i = 0; i < 2; ++i) {
        int rr = r0 + wm * 32 + i * 16 + lr;
        #pragma unroll
        for (int j = 0; j < 4; ++j) {
            #pragma unroll
            for (int e = 0; e < 4; ++e) {
                int oc = n0 + wn * 64 + j * 16 + lq * 4 + e;
                out[((size_t)b * NOC + oc) * 1024 + rr] = acc[i][j][e];
            }
        }
    }
}

// ---------------- round-1 fp32 fallback (ws too small) ----------------
__global__ __launch_bounds__(256) void bcc_gemm_f32(
    const float* __restrict__ x, const float* __restrict__ w,
    float* __restrict__ out) {
    __shared__ float Asf[64][68];
    __shared__ float Wsf[64][68];
    const int tid = threadIdx.x;
    const int tn = tid & 15, tm = tid >> 4;
    const int p = blockIdx.x;
    const int m0 = blockIdx.y * 64;
    const int b = m0 >> 10, r0 = m0 & 1023;
    const float* xb = x + (size_t)b * (256 * 32 * 32);
    float acc[4][4] = {};
    for (int q = 0; q < QB; ++q) {
        #pragma unroll
        for (int i = 0; i < 16; ++i) {
            int idx = i * 256 + tid;
            int s = idx & 63, mm = idx >> 6;
            int flat = (r0 + mm) * QK + q * 64 + s;
            int feat = flat >> 10, loc = flat & 1023;
            int c = feat / 9, kk = feat - c * 9;
            int hi = (loc >> 5) + (kk / 3) - 1;
            int wi = (loc & 31) + (kk % 3) - 1;
            float v = 0.0f;
            if ((unsigned)hi < 32u && (unsigned)wi < 32u)
                v = xb[(c * 32 + hi) * 32 + wi];
            Asf[mm][s] = v;
        }
        const float* wb = w + (p * QB + q) * 64;
        #pragma unroll
        for (int i = 0; i < 16; ++i) {
            int idx = i * 256 + tid;
            int t = idx & 63, s = idx >> 6;
            Wsf[s][t] = wb[(t - s) & 63];
        }
        __syncthreads();
        #pragma unroll
        for (int s0 = 0; s0 < 64; s0 += 4) {
            float4 a4[4], b4[4];
            #pragma unroll
            for (int i2 = 0; i2 < 4; ++i2)
                a4[i2] = *(const float4*)&Asf[tm * 4 + i2][s0];
            #pragma unroll
            for (int ss = 0; ss < 4; ++ss)
                b4[ss] = *(const float4*)&Wsf[s0 + ss][tn * 4];
            #pragma unroll
            for (int i2 = 0; i2 < 4; ++i2) {
                const float* av = (const float*)&a4[i2];
                #pragma unroll
                for (int ss = 0; ss < 4; ++ss) {
                    float a = av[ss];
                    acc[i2][0] += a * b4[ss].x;
                    acc[i2][1] += a * b4[ss].y;
                    acc[i2][2] += a * b4[ss].z;
                    acc[i2][3] += a * b4[ss].w;
                }
            }
        }
        __syncthreads();
    }
    float* outb = out + (size_t)b * NOC * 1024;
    const int r_base = r0 + tm * 4;
    #pragma unroll
    for (int j = 0; j < 4; ++j) {
        int oc = p * 64 + tn * 4 + j;
        float4 v = make_float4(acc[0][j], acc[1][j], acc[2][j], acc[3][j]);
        *(float4*)&outb[(size_t)oc * 1024 + r_base] = v;
    }
}

extern "C" void kernel_launch(void* const* d_in, const int* in_sizes, int n_in,
                              void* d_out, int out_size, void* d_ws, size_t ws_size,
                              hipStream_t stream) {
    const float* x = (const float*)d_in[0];
    const float* w = (const float*)d_in[1];
    float* out = (float*)d_out;

    const size_t bytesA = (size_t)MROWS * QK * sizeof(ushort);  // 37,748,736
    const size_t bytesB = (size_t)NOC * QK * sizeof(ushort);    //  2,359,296

    if (ws_size >= bytesA + bytesB) {
        ushort* wsA = (ushort*)d_ws;
        ushort* wsB = (ushort*)((char*)d_ws + bytesA);
        bcc_prep<<<PREP_A_BLOCKS + PREP_B_BLOCKS, 256, 0, stream>>>(x, w, wsA, wsB);
        bcc_mfma<<<512, 256, 0, stream>>>(wsA, wsB, out);
    } else {
        bcc_gemm_f32<<<dim3(8, MROWS / 64), 256, 0, stream>>>(x, w, out);
    }
}

// Round 7
// 94.949 us; speedup vs baseline: 1.2142x; 1.2142x over previous
//
#include <hip/hip_runtime.h>
#include <hip/hip_bf16.h>

// Block-circulant conv == GEMM  out[b,oc,r] = sum_k A[b*1024+r, k] * B[k, oc]
//   A = im2col(x) per batch, contiguous (1024, 2304) view (reference reshape).
//   B[k,oc] = w[oc>>6][k>>6][((oc&63)-(k&63))&63]  (circulant expansion)
//
// R7: (1) prep v3 — one block per (b,c): image -> LDS once, emit all 9
//     shifted/masked bf16 copies (x read 1x instead of 9x; write-bound).
//     (2) GEMM = R5 structure (grid 256, 512 thr, 64x64 wave-tiles,
//     2-way k-interleave + LDS combine, XOR swizzle) with TRIPLE-buffered
//     staging: stage(q+2) issued each iter, s_waitcnt vmcnt(8) drains only
//     stage(q) -> 2 iterations of VMEM slack (R5/R6 had 1).
//     R6's 2-blocks/CU experiment REGRESSED (105->115): reverted.

#define QK 2304
#define MROWS 8192
#define NOC 512
#define QB 36

typedef __attribute__((ext_vector_type(8))) short short8;
typedef __attribute__((ext_vector_type(4))) float floatx4;

__device__ __forceinline__ ushort f2bf(float f) {
    __hip_bfloat16 h = __float2bfloat16(f);
    return *reinterpret_cast<ushort*>(&h);
}

__device__ __forceinline__ void async16(const void* g, void* l) {
    __builtin_amdgcn_global_load_lds((const __attribute__((address_space(1))) void*)g,
                                     (__attribute__((address_space(3))) void*)l, 16, 0, 0);
}

// ---------------- prep v3: A im2col (read-once-write-9) + B expand ----------------
#define PREP_A_BLOCKS 2048    // 8 b * 256 c
#define PREP_B_BLOCKS 576     // 512 rows * 288 8-elem chunks / 256

__global__ __launch_bounds__(256) void bcc_prep(const float* __restrict__ x,
                                                const float* __restrict__ w,
                                                ushort* __restrict__ wsA,
                                                ushort* __restrict__ wsB) {
    if (blockIdx.x < PREP_A_BLOCKS) {
        __shared__ float img[1024];
        const int bb = blockIdx.x >> 8, c = blockIdx.x & 255;
        const float* src = x + ((size_t)bb * 256 + c) * 1024;
        *(float4*)&img[threadIdx.x * 4] = *(const float4*)&src[threadIdx.x * 4];
        __syncthreads();

        const int loc0 = threadIdx.x * 4;
        ushort* dstbase = wsA + ((size_t)bb * 2304 + c * 9) * 1024 + loc0;
        #pragma unroll
        for (int kk = 0; kk < 9; ++kk) {
            const int di = kk / 3, dj = kk - di * 3;
            const int off = (di - 1) * 32 + (dj - 1);
            const bool row_ok = (unsigned)((loc0 >> 5) + di - 1) < 32u;
            ushort u[4];
            #pragma unroll
            for (int e = 0; e < 4; ++e) {
                int wi = ((loc0 + e) & 31) + dj - 1;
                bool ok = row_ok && ((unsigned)wi < 32u);
                float v = ok ? img[loc0 + e + off] : 0.f;
                u[e] = f2bf(v);
            }
            *(ushort4*)&dstbase[(size_t)kk * 1024] = make_ushort4(u[0], u[1], u[2], u[3]);
        }
    } else {
        int t = (blockIdx.x - PREP_A_BLOCKS) * 256 + threadIdx.x;  // 0..147455
        int n = t / 288;
        int o = t - n * 288;
        int p = n >> 6, tt = n & 63;
        int k0 = o * 8;
        ushort u[8];
        #pragma unroll
        for (int e = 0; e < 8; ++e) {
            int k = k0 + e;
            int q = k >> 6, s = k & 63;
            u[e] = f2bf(w[(p * QB + q) * 64 + ((tt - s) & 63)]);
        }
        *(ushort4*)&wsB[(size_t)n * QK + k0]     = make_ushort4(u[0], u[1], u[2], u[3]);
        *(ushort4*)&wsB[(size_t)n * QK + k0 + 4] = make_ushort4(u[4], u[5], u[6], u[7]);
    }
}

// ---------------- main GEMM: 128x128 tile, 8 waves, 64x64 wave-tiles,
// ---------------- 2-way k-interleave, TRIPLE-buffer + raw vmcnt(8) --------
__global__ __launch_bounds__(512) void bcc_mfma(const ushort* __restrict__ A,
                                                const ushort* __restrict__ Bm,
                                                float* __restrict__ out) {
    __shared__ ushort smem[3][2][128 * 64];   // [buf][A/B][row*64+chunk] 96 KB

    const int tid = threadIdx.x;
    const int l = tid & 63, w = tid >> 6;      // 8 waves
    const int t3 = w & 3, ks = w >> 2;         // tile id, k-half
    const int wm = t3 & 1, wn = t3 >> 1;       // 2x2 grid of 64x64 tiles

    // XCD-affinity decode: 4 blocks sharing an A-tile -> same (lin&7) == XCD
    const int lin = blockIdx.x;                // 0..255
    const int n_idx = (lin >> 3) & 3;
    const int m_idx = ((lin >> 5) << 3) | (lin & 7);
    const int n0 = n_idx * 128;
    const int m0 = m_idx * 128;
    const int b  = m0 >> 10, r0 = m0 & 1023;

    const int lr = l & 15, lq = l >> 4;        // quarter-wave split
    const int lrow = l >> 3;                   // staging row in 8-group
    const int lkoff = ((l & 7) ^ (lrow & 7)) * 8;  // swizzled source chunk

    floatx4 acc[4][4];
    #pragma unroll
    for (int i = 0; i < 4; ++i)
        #pragma unroll
        for (int j = 0; j < 4; ++j) acc[i][j] = (floatx4){0.f, 0.f, 0.f, 0.f};

    auto stage = [&](int q, int buf) {
        const int kb = q * 64;
        #pragma unroll
        for (int t = 0; t < 2; ++t) {
            int row8 = w * 16 + t * 8;
            async16(A  + ((size_t)(m0 + row8 + lrow) * QK + kb + lkoff),
                    &smem[buf][0][row8 * 64]);
            async16(Bm + ((size_t)(n0 + row8 + lrow) * QK + kb + lkoff),
                    &smem[buf][1][row8 * 64]);
        }
    };

    stage(0, 0);
    stage(1, 1);
    const int ca = ks * 4 + lq;                // logical 16B chunk (k-half)
    for (int q = 0; q < QB; ++q) {
        const int buf = q % 3;
        if (q + 2 < QB) {
            stage(q + 2, (q + 2) % 3);
            asm volatile("s_waitcnt vmcnt(8)" ::: "memory");  // drain stage(q) only
        } else if (q + 1 < QB) {
            asm volatile("s_waitcnt vmcnt(4)" ::: "memory");
        } else {
            asm volatile("s_waitcnt vmcnt(0)" ::: "memory");
        }
        __builtin_amdgcn_s_barrier();
        asm volatile("" ::: "memory");

        short8 av[4], bv[4];
        #pragma unroll
        for (int i = 0; i < 4; ++i) {
            int Ra = wm * 64 + i * 16 + lr;
            av[i] = *(const short8*)&smem[buf][0][Ra * 64 + ((ca ^ (Ra & 7)) * 8)];
        }
        #pragma unroll
        for (int j = 0; j < 4; ++j) {
            int Rb = wn * 64 + j * 16 + lr;
            bv[j] = *(const short8*)&smem[buf][1][Rb * 64 + ((ca ^ (Rb & 7)) * 8)];
        }
        // operand-swapped: D rows = oc, cols = r (r-contiguous stores)
        #pragma unroll
        for (int i = 0; i < 4; ++i)
            #pragma unroll
            for (int j = 0; j < 4; ++j)
                acc[i][j] = __builtin_amdgcn_mfma_f32_16x16x32_bf16(bv[j], av[i], acc[i][j], 0, 0, 0);

        asm volatile("" ::: "memory");
        __builtin_amdgcn_s_barrier();
    }

    // ---- combine k-halves through LDS, then store ----
    __syncthreads();
    float* fsm = (float*)&smem[0][0][0];       // 64 KB of the 96 KB
    if (ks == 1) {
        #pragma unroll
        for (int i = 0; i < 4; ++i)
            #pragma unroll
            for (int j = 0; j < 4; ++j)
                *(floatx4*)&fsm[t3 * 4096 + (i * 4 + j) * 256 + l * 4] = acc[i][j];
    }
    __syncthreads();
    if (ks == 0) {
        #pragma unroll
        for (int i = 0; i < 4; ++i) {
            int rr = r0 + wm * 64 + i * 16 + lr;
            #pragma unroll
            for (int j = 0; j < 4; ++j) {
                floatx4 o4 = *(const floatx4*)&fsm[t3 * 4096 + (i * 4 + j) * 256 + l * 4];
                #pragma unroll
                for (int e = 0; e < 4; ++e) {
                    int oc = n0 + wn * 64 + j * 16 + lq * 4 + e;
                    out[((size_t)b * NOC + oc) * 1024 + rr] = acc[i][j][e] + o4[e];
                }
            }
        }
    }
}

// ---------------- round-1 fp32 fallback (ws too small) ----------------
__global__ __launch_bounds__(256) void bcc_gemm_f32(
    const float* __restrict__ x, const float* __restrict__ w,
    float* __restrict__ out) {
    __shared__ float Asf[64][68];
    __shared__ float Wsf[64][68];
    const int tid = threadIdx.x;
    const int tn = tid & 15, tm = tid >> 4;
    const int p = blockIdx.x;
    const int m0 = blockIdx.y * 64;
    const int b = m0 >> 10, r0 = m0 & 1023;
    const float* xb = x + (size_t)b * (256 * 32 * 32);
    float acc[4][4] = {};
    for (int q = 0; q < QB; ++q) {
        #pragma unroll
        for (int i = 0; i < 16; ++i) {
            int idx = i * 256 + tid;
            int s = idx & 63, mm = idx >> 6;
            int flat = (r0 + mm) * QK + q * 64 + s;
            int feat = flat >> 10, loc = flat & 1023;
            int c = feat / 9, kk = feat - c * 9;
            int hi = (loc >> 5) + (kk / 3) - 1;
            int wi = (loc & 31) + (kk % 3) - 1;
            float v = 0.0f;
            if ((unsigned)hi < 32u && (unsigned)wi < 32u)
                v = xb[(c * 32 + hi) * 32 + wi];
            Asf[mm][s] = v;
        }
        const float* wb = w + (p * QB + q) * 64;
        #pragma unroll
        for (int i = 0; i < 16; ++i) {
            int idx = i * 256 + tid;
            int t = idx & 63, s = idx >> 6;
            Wsf[s][t] = wb[(t - s) & 63];
        }
        __syncthreads();
        #pragma unroll
        for (int s0 = 0; s0 < 64; s0 += 4) {
            float4 a4[4], b4[4];
            #pragma unroll
            for (int i2 = 0; i2 < 4; ++i2)
                a4[i2] = *(const float4*)&Asf[tm * 4 + i2][s0];
            #pragma unroll
            for (int ss = 0; ss < 4; ++ss)
                b4[ss] = *(const float4*)&Wsf[s0 + ss][tn * 4];
            #pragma unroll
            for (int i2 = 0; i2 < 4; ++i2) {
                const float* av = (const float*)&a4[i2];
                #pragma unroll
                for (int ss = 0; ss < 4; ++ss) {
                    float a = av[ss];
                    acc[i2][0] += a * b4[ss].x;
                    acc[i2][1] += a * b4[ss].y;
                    acc[i2][2] += a * b4[ss].z;
                    acc[i2][3] += a * b4[ss].w;
                }
            }
        }
        __syncthreads();
    }
    float* outb = out + (size_t)b * NOC * 1024;
    const int r_base = r0 + tm * 4;
    #pragma unroll
    for (int j = 0; j < 4; ++j) {
        int oc = p * 64 + tn * 4 + j;
        float4 v = make_float4(acc[0][j], acc[1][j], acc[2][j], acc[3][j]);
        *(float4*)&outb[(size_t)oc * 1024 + r_base] = v;
    }
}

extern "C" void kernel_launch(void* const* d_in, const int* in_sizes, int n_in,
                              void* d_out, int out_size, void* d_ws, size_t ws_size,
                              hipStream_t stream) {
    const float* x = (const float*)d_in[0];
    const float* w = (const float*)d_in[1];
    float* out = (float*)d_out;

    const size_t bytesA = (size_t)MROWS * QK * sizeof(ushort);  // 37,748,736
    const size_t bytesB = (size_t)NOC * QK * sizeof(ushort);    //  2,359,296

    if (ws_size >= bytesA + bytesB) {
        ushort* wsA = (ushort*)d_ws;
        ushort* wsB = (ushort*)((char*)d_ws + bytesA);
        bcc_prep<<<PREP_A_BLOCKS + PREP_B_BLOCKS, 256, 0, stream>>>(x, w, wsA, wsB);
        bcc_mfma<<<256, 512, 0, stream>>>(wsA, wsB, out);
    } else {
        bcc_gemm_f32<<<dim3(8, MROWS / 64), 256, 0, stream>>>(x, w, out);
    }
}